// Round 3
// baseline (986.315 us; speedup 1.0000x reference)
//
#include <hip/hip_runtime.h>
#include <math.h>

// NSMCell: N=50000, E=800000, H=128, P=8, B=512
#define H_DIM 128
#define NPROP 8
#define NGRAPHS 512
#define WSTRIDE 136      // padded k-stride in ushorts (272B rows -> conflict-free-ish)
#define PHASE_USH 34816  // 2*128*136 ushorts per phase block (hi then lo)

typedef short short8 __attribute__((ext_vector_type(8)));
typedef float f32x4 __attribute__((ext_vector_type(4)));
typedef unsigned short ushort_t;

// split fp32 -> bf16 hi (truncated) + bf16 lo (rounded residual): ~17-bit mantissa
__device__ __forceinline__ void split_bf16(float x, ushort_t& hb, ushort_t& lb) {
  unsigned u = __float_as_uint(x);
  hb = (ushort_t)(u >> 16);
  float hf = __uint_as_float(u & 0xFFFF0000u);
  float lf = x - hf;
  unsigned ul = __float_as_uint(lf);
  lb = (ushort_t)((ul + 0x8000u) >> 16);
}

__device__ __forceinline__ void cvt8(float4 a, float4 b, short8& hi, short8& lo) {
  float f[8] = {a.x, a.y, a.z, a.w, b.x, b.y, b.z, b.w};
#pragma unroll
  for (int i = 0; i < 8; ++i) {
    ushort_t h, l;
    split_bf16(f[i], h, l);
    hi[i] = (short)h;
    lo[i] = (short)l;
  }
}

__device__ __forceinline__ float elu_f(float y) {
  return y > 0.f ? y : (__expf(y) - 1.f);
}

typedef const __attribute__((address_space(1))) unsigned int gas_uint;
typedef __attribute__((address_space(3))) unsigned int las_uint;

// async copy one 69632B phase block global->LDS (width-16 global_load_lds).
// Global layout is pre-padded so lane order == LDS order (wave-uniform base + lane*16).
__device__ __forceinline__ void stage_weights(const ushort_t* __restrict__ src,
                                              ushort_t* lds) {
  const int t = threadIdx.x;
  const int wbase = t & ~63;  // wave-uniform
#pragma unroll
  for (int j = 0; j < 17; ++j) {
    int chunk = j * 256 + t;       // per-lane 16B chunk id
    int wchunk = j * 256 + wbase;  // wave-uniform LDS base chunk
    __builtin_amdgcn_global_load_lds((gas_uint*)(src + chunk * 8),
                                     (las_uint*)(lds + wchunk * 8), 16, 0, 0);
  }
}

// ---------------------------------------------------------------------------
__global__ void prep_prop_sim(const float* __restrict__ prop_embeds,
                              const float* __restrict__ instruction,
                              float* __restrict__ prop_sim) {
  __shared__ float dots[NPROP];
  int wave = threadIdx.x >> 6;
  int lane = threadIdx.x & 63;
  float v = prop_embeds[wave * H_DIM + lane] * instruction[lane] +
            prop_embeds[wave * H_DIM + 64 + lane] * instruction[64 + lane];
#pragma unroll
  for (int off = 32; off > 0; off >>= 1) v += __shfl_down(v, off);
  if (lane == 0) dots[wave] = v;
  __syncthreads();
  if (threadIdx.x == 0) {
    float m = dots[0];
    for (int p = 1; p < NPROP; ++p) m = fmaxf(m, dots[p]);
    float e[NPROP], s = 0.f;
    for (int p = 0; p < NPROP; ++p) { e[p] = expf(dots[p] - m); s += e[p]; }
    for (int p = 0; p < NPROP; ++p) prop_sim[p] = e[p] / s;
  }
}

// ---------------------------------------------------------------------------
// Fold prop_sim[p]*instruction[h] into weights; write PADDED hi/lo blocks so
// each 69632B phase block can be byte-copied to LDS by global_load_lds.
__global__ void prep_weights(const float* __restrict__ Ws,
                             const float* __restrict__ instruction,
                             const float* __restrict__ prop_sim,
                             ushort_t* __restrict__ Wpk) {
  int idx = blockIdx.x * 256 + threadIdx.x;  // < 131072
  int p = idx >> 14;
  int h = (idx >> 7) & 127;
  int k = idx & 127;
  float s = (p < 7) ? prop_sim[p] : 1.0f;
  float w = s * instruction[h] * Ws[idx];
  ushort_t hb, lb;
  split_bf16(w, hb, lb);
  size_t base = (size_t)p * PHASE_USH + (size_t)h * WSTRIDE + k;
  Wpk[base] = hb;
  Wpk[base + 17408] = lb;  // lo half-block (128*136)
}

// ---------------------------------------------------------------------------
// Edge pass: persistent grid-stride over 128-edge tiles. Weights in LDS
// (staged once), B fragments per-lane from global with depth-1 tile prefetch.
// NO barriers in the main loop.
__global__ void __launch_bounds__(256, 2) edge_mfma_kernel(
    const float* __restrict__ edge_attrs,   // [E][128]
    const ushort_t* __restrict__ Wpk7,      // phase-7 padded block
    const float* __restrict__ W_relation,   // [128]
    const float* __restrict__ distribution, // [N]
    const int* __restrict__ src_idx,        // [E]
    const int* __restrict__ dst_idx,        // [E]
    float* __restrict__ rel_logits,         // [N] zero-init
    int num_tiles) {
  __shared__ __align__(16) ushort_t WA[PHASE_USH];
  const int t = threadIdx.x;
  const int lane = t & 63, wave = t >> 6;
  const int col = lane & 15, quad = lane >> 4;
  const int r0 = wave * 32 + col;

  stage_weights(Wpk7, WA);

  float4 raw[16];
  int tile = blockIdx.x;
  {
    const float* b0 = edge_attrs + ((long)tile * 128 + r0) * H_DIM;
#pragma unroll
    for (int ks = 0; ks < 4; ++ks) {
      int k0 = ks * 32 + quad * 8;
      raw[ks * 4 + 0] = *(const float4*)(b0 + k0);
      raw[ks * 4 + 1] = *(const float4*)(b0 + k0 + 4);
      raw[ks * 4 + 2] = *(const float4*)(b0 + 16 * H_DIM + k0);
      raw[ks * 4 + 3] = *(const float4*)(b0 + 16 * H_DIM + k0 + 4);
    }
  }
  __syncthreads();  // weights staged (drains vmcnt incl. first raw)

  while (true) {
    short8 bh[4][2], bl[4][2];
#pragma unroll
    for (int ks = 0; ks < 4; ++ks) {
      cvt8(raw[ks * 4 + 0], raw[ks * 4 + 1], bh[ks][0], bl[ks][0]);
      cvt8(raw[ks * 4 + 2], raw[ks * 4 + 3], bh[ks][1], bl[ks][1]);
    }
    const long cur = tile;
    tile += gridDim.x;
    if (tile < num_tiles) {  // depth-1 prefetch of next tile
      const float* b0 = edge_attrs + ((long)tile * 128 + r0) * H_DIM;
#pragma unroll
      for (int ks = 0; ks < 4; ++ks) {
        int k0 = ks * 32 + quad * 8;
        raw[ks * 4 + 0] = *(const float4*)(b0 + k0);
        raw[ks * 4 + 1] = *(const float4*)(b0 + k0 + 4);
        raw[ks * 4 + 2] = *(const float4*)(b0 + 16 * H_DIM + k0);
        raw[ks * 4 + 3] = *(const float4*)(b0 + 16 * H_DIM + k0 + 4);
      }
    }

    f32x4 acc[8][2];
#pragma unroll
    for (int m = 0; m < 8; ++m) {
      acc[m][0] = (f32x4){0.f, 0.f, 0.f, 0.f};
      acc[m][1] = (f32x4){0.f, 0.f, 0.f, 0.f};
    }
#pragma unroll
    for (int ks = 0; ks < 4; ++ks) {
      const int k0 = ks * 32 + quad * 8;
#pragma unroll
      for (int m = 0; m < 8; ++m) {
        const int hrow = m * 16 + col;
        short8 ah = *(const short8*)&WA[hrow * WSTRIDE + k0];
        short8 al = *(const short8*)&WA[17408 + hrow * WSTRIDE + k0];
        acc[m][0] = __builtin_amdgcn_mfma_f32_16x16x32_bf16(ah, bh[ks][0], acc[m][0], 0, 0, 0);
        acc[m][0] = __builtin_amdgcn_mfma_f32_16x16x32_bf16(ah, bl[ks][0], acc[m][0], 0, 0, 0);
        acc[m][0] = __builtin_amdgcn_mfma_f32_16x16x32_bf16(al, bh[ks][0], acc[m][0], 0, 0, 0);
        acc[m][1] = __builtin_amdgcn_mfma_f32_16x16x32_bf16(ah, bh[ks][1], acc[m][1], 0, 0, 0);
        acc[m][1] = __builtin_amdgcn_mfma_f32_16x16x32_bf16(ah, bl[ks][1], acc[m][1], 0, 0, 0);
        acc[m][1] = __builtin_amdgcn_mfma_f32_16x16x32_bf16(al, bh[ks][1], acc[m][1], 0, 0, 0);
      }
    }

    // epilogue: s_e = sum_h W_rel[h]*elu(C[h,e]); C row = m*16+quad*4+reg
    float s0 = 0.f, s1 = 0.f;
#pragma unroll
    for (int m = 0; m < 8; ++m) {
      float4 wv = *(const float4*)(W_relation + m * 16 + quad * 4);
      s0 += wv.x * elu_f(acc[m][0][0]) + wv.y * elu_f(acc[m][0][1]) +
            wv.z * elu_f(acc[m][0][2]) + wv.w * elu_f(acc[m][0][3]);
      s1 += wv.x * elu_f(acc[m][1][0]) + wv.y * elu_f(acc[m][1][1]) +
            wv.z * elu_f(acc[m][1][2]) + wv.w * elu_f(acc[m][1][3]);
    }
    s0 += __shfl_xor(s0, 16); s0 += __shfl_xor(s0, 32);
    s1 += __shfl_xor(s1, 16); s1 += __shfl_xor(s1, 32);
    if (lane < 32) {
      long e = cur * 128 + wave * 32 + lane;
      float sv = (lane & 16) ? s1 : s0;
      atomicAdd(rel_logits + dst_idx[e], distribution[src_idx[e]] * sv);
    }
    if (tile >= num_tiles) break;
  }
}

// ---------------------------------------------------------------------------
// Node pass: one 128-node tile per block; K=896 as 7 phases. Per phase:
// restage that phase's weights into LDS; B fragments per-lane from global
// with depth-1 phase prefetch issued AFTER the staging barrier.
__global__ void __launch_bounds__(256, 2) node_mfma_kernel(
    const float* __restrict__ node_attrs,  // [N][7][128]
    const ushort_t* __restrict__ Wpk,      // phases 0..6 padded blocks
    const float* __restrict__ W_state,     // [128]
    float* __restrict__ state_logits,      // [N]
    int N) {
  __shared__ __align__(16) ushort_t WA[PHASE_USH];
  const int t = threadIdx.x;
  const int lane = t & 63, wave = t >> 6;
  const int col = lane & 15, quad = lane >> 4;
  const int r0 = wave * 32 + col;
  const long tile_base = (long)blockIdx.x * 128;

  long n0 = tile_base + r0;
  long n1 = n0 + 16;
  long nc0 = n0 < N ? n0 : (long)(N - 1);  // clamp OOB rows (dead lanes)
  long nc1 = n1 < N ? n1 : (long)(N - 1);
  const float* rp0 = node_attrs + nc0 * 7 * H_DIM;
  const float* rp1 = node_attrs + nc1 * 7 * H_DIM;

  float4 raw[16];
#pragma unroll
  for (int ks = 0; ks < 4; ++ks) {  // phase 0 preload
    int k0 = ks * 32 + quad * 8;
    raw[ks * 4 + 0] = *(const float4*)(rp0 + k0);
    raw[ks * 4 + 1] = *(const float4*)(rp0 + k0 + 4);
    raw[ks * 4 + 2] = *(const float4*)(rp1 + k0);
    raw[ks * 4 + 3] = *(const float4*)(rp1 + k0 + 4);
  }

  f32x4 acc[8][2];
#pragma unroll
  for (int m = 0; m < 8; ++m) {
    acc[m][0] = (f32x4){0.f, 0.f, 0.f, 0.f};
    acc[m][1] = (f32x4){0.f, 0.f, 0.f, 0.f};
  }

  for (int p = 0; p < 7; ++p) {
    __syncthreads();  // WA WAR vs previous phase's MFMA reads; drains raw p
    stage_weights(Wpk + (size_t)p * PHASE_USH, WA);
    short8 bh[4][2], bl[4][2];
#pragma unroll
    for (int ks = 0; ks < 4; ++ks) {
      cvt8(raw[ks * 4 + 0], raw[ks * 4 + 1], bh[ks][0], bl[ks][0]);
      cvt8(raw[ks * 4 + 2], raw[ks * 4 + 3], bh[ks][1], bl[ks][1]);
    }
    __syncthreads();  // weights staged (drains the 68KB L2 copy)
    if (p < 6) {      // prefetch next phase's B rows during MFMA
      const float* q0 = rp0 + (p + 1) * H_DIM;
      const float* q1 = rp1 + (p + 1) * H_DIM;
#pragma unroll
      for (int ks = 0; ks < 4; ++ks) {
        int k0 = ks * 32 + quad * 8;
        raw[ks * 4 + 0] = *(const float4*)(q0 + k0);
        raw[ks * 4 + 1] = *(const float4*)(q0 + k0 + 4);
        raw[ks * 4 + 2] = *(const float4*)(q1 + k0);
        raw[ks * 4 + 3] = *(const float4*)(q1 + k0 + 4);
      }
    }
#pragma unroll
    for (int ks = 0; ks < 4; ++ks) {
      const int k0 = ks * 32 + quad * 8;
#pragma unroll
      for (int m = 0; m < 8; ++m) {
        const int hrow = m * 16 + col;
        short8 ah = *(const short8*)&WA[hrow * WSTRIDE + k0];
        short8 al = *(const short8*)&WA[17408 + hrow * WSTRIDE + k0];
        acc[m][0] = __builtin_amdgcn_mfma_f32_16x16x32_bf16(ah, bh[ks][0], acc[m][0], 0, 0, 0);
        acc[m][0] = __builtin_amdgcn_mfma_f32_16x16x32_bf16(ah, bl[ks][0], acc[m][0], 0, 0, 0);
        acc[m][0] = __builtin_amdgcn_mfma_f32_16x16x32_bf16(al, bh[ks][0], acc[m][0], 0, 0, 0);
        acc[m][1] = __builtin_amdgcn_mfma_f32_16x16x32_bf16(ah, bh[ks][1], acc[m][1], 0, 0, 0);
        acc[m][1] = __builtin_amdgcn_mfma_f32_16x16x32_bf16(ah, bl[ks][1], acc[m][1], 0, 0, 0);
        acc[m][1] = __builtin_amdgcn_mfma_f32_16x16x32_bf16(al, bh[ks][1], acc[m][1], 0, 0, 0);
      }
    }
  }

  float s0 = 0.f, s1 = 0.f;
#pragma unroll
  for (int m = 0; m < 8; ++m) {
    float4 wv = *(const float4*)(W_state + m * 16 + quad * 4);
    s0 += wv.x * elu_f(acc[m][0][0]) + wv.y * elu_f(acc[m][0][1]) +
          wv.z * elu_f(acc[m][0][2]) + wv.w * elu_f(acc[m][0][3]);
    s1 += wv.x * elu_f(acc[m][1][0]) + wv.y * elu_f(acc[m][1][1]) +
          wv.z * elu_f(acc[m][1][2]) + wv.w * elu_f(acc[m][1][3]);
  }
  s0 += __shfl_xor(s0, 16); s0 += __shfl_xor(s0, 32);
  s1 += __shfl_xor(s1, 16); s1 += __shfl_xor(s1, 32);
  if (lane < 32) {
    long n = tile_base + wave * 32 + lane;
    if (n < N) state_logits[n] = (lane & 16) ? s1 : s0;
  }
}

// ---------------------------------------------------------------------------
__device__ __forceinline__ float wave_red_max(float v) {
#pragma unroll
  for (int off = 32; off > 0; off >>= 1) v = fmaxf(v, __shfl_down(v, off));
  return v;
}
__device__ __forceinline__ float wave_red_sum(float v) {
#pragma unroll
  for (int off = 32; off > 0; off >>= 1) v += __shfl_down(v, off);
  return v;
}

__global__ void finalize_kernel(const float* __restrict__ state_logits,
                                const float* __restrict__ rel_logits,
                                const int* __restrict__ node_graph,
                                const float* __restrict__ prop_sim,
                                float* __restrict__ out, int N) {
  int g = blockIdx.x;
  __shared__ int bounds[2];
  if (threadIdx.x == 0) {
    int a = 0, b = N;
    while (a < b) { int m = (a + b) >> 1; if (node_graph[m] < g) a = m + 1; else b = m; }
    bounds[0] = a;
    b = N;
    while (a < b) { int m = (a + b) >> 1; if (node_graph[m] < g + 1) a = m + 1; else b = m; }
    bounds[1] = a;
  }
  __syncthreads();
  int lo = bounds[0], hi = bounds[1];
  if (lo >= hi) return;

  int lane = threadIdx.x & 63, w = threadIdx.x >> 6;
  __shared__ float redS[4], redR[4];

  float mS = -3.0e38f, mR = -3.0e38f;
  for (int i = lo + threadIdx.x; i < hi; i += blockDim.x) {
    mS = fmaxf(mS, state_logits[i]);
    mR = fmaxf(mR, rel_logits[i]);
  }
  mS = wave_red_max(mS); mR = wave_red_max(mR);
  if (lane == 0) { redS[w] = mS; redR[w] = mR; }
  __syncthreads();
  mS = fmaxf(fmaxf(redS[0], redS[1]), fmaxf(redS[2], redS[3]));
  mR = fmaxf(fmaxf(redR[0], redR[1]), fmaxf(redR[2], redR[3]));
  __syncthreads();

  float sS = 0.f, sR = 0.f;
  for (int i = lo + threadIdx.x; i < hi; i += blockDim.x) {
    sS += expf(state_logits[i] - mS);
    sR += expf(rel_logits[i] - mR);
  }
  sS = wave_red_sum(sS); sR = wave_red_sum(sR);
  if (lane == 0) { redS[w] = sS; redR[w] = sR; }
  __syncthreads();
  sS = redS[0] + redS[1] + redS[2] + redS[3];
  sR = redR[0] + redR[1] + redR[2] + redR[3];

  float p_rel = prop_sim[NPROP - 1];
  float invS = 1.0f / sS, invR = 1.0f / sR;
  for (int i = lo + threadIdx.x; i < hi; i += blockDim.x) {
    float ps = expf(state_logits[i] - mS) * invS;
    float pr = expf(rel_logits[i] - mR) * invR;
    out[i] = p_rel * pr + (1.0f - p_rel) * ps;
  }
}

// ---------------------------------------------------------------------------
extern "C" void kernel_launch(void* const* d_in, const int* in_sizes, int n_in,
                              void* d_out, int out_size, void* d_ws, size_t ws_size,
                              hipStream_t stream) {
  const float* node_attrs   = (const float*)d_in[0];
  const float* edge_attrs   = (const float*)d_in[1];
  const float* instruction  = (const float*)d_in[2];
  const float* prop_embeds  = (const float*)d_in[3];
  const float* distribution = (const float*)d_in[4];
  const float* Ws_property  = (const float*)d_in[5];
  const float* W_state      = (const float*)d_in[6];
  const float* W_relation   = (const float*)d_in[7];
  const int*   edge_indices = (const int*)d_in[8];
  const int*   node_graph   = (const int*)d_in[9];

  int N = in_sizes[4];
  int E = in_sizes[1] / H_DIM;
  float* out = (float*)d_out;

  char* w = (char*)d_ws;
  size_t nBytes = ((size_t)N * 4 + 15) & ~(size_t)15;
  float*    prop_sim     = (float*)w;                      // 256 B
  float*    state_logits = (float*)(w + 256);
  float*    rel_logits   = (float*)(w + 256 + nBytes);
  ushort_t* Wpk          = (ushort_t*)(w + 256 + 2 * nBytes);  // 8*69632 B padded

  hipMemsetAsync(rel_logits, 0, (size_t)N * 4, stream);

  prep_prop_sim<<<1, 512, 0, stream>>>(prop_embeds, instruction, prop_sim);
  prep_weights<<<NPROP * H_DIM * H_DIM / 256, 256, 0, stream>>>(
      Ws_property, instruction, prop_sim, Wpk);

  node_mfma_kernel<<<(N + 127) / 128, 256, 0, stream>>>(
      node_attrs, Wpk, W_state, state_logits, N);

  int num_tiles = E / 128;  // 6250
  edge_mfma_kernel<<<512, 256, 0, stream>>>(
      edge_attrs, Wpk + (size_t)7 * PHASE_USH, W_relation, distribution,
      edge_indices, edge_indices + E, rel_logits, num_tiles);

  finalize_kernel<<<NGRAPHS, 256, 0, stream>>>(state_logits, rel_logits,
                                               node_graph, prop_sim, out, N);
}